// Round 3
// baseline (1108.805 us; speedup 1.0000x reference)
//
#include <hip/hip_runtime.h>
#include <hip/hip_bf16.h>
#include <cstdint>

#define S_LEN 2304
#define NDIM  3072
#define NH    24
#define HD    128

typedef unsigned short u16;
typedef __bf16  bf16x8  __attribute__((ext_vector_type(8)));
typedef float   floatx4 __attribute__((ext_vector_type(4)));

__device__ __forceinline__ u16 f2bf(float x) {
  union { float f; unsigned int u; } a; a.f = x;
  unsigned int r = (a.u + 0x7FFFu + ((a.u >> 16) & 1u)) >> 16;
  return (u16)r;
}

// async 16B global->LDS (direct-to-shared DMA). LDS dest must be
// wave-uniform base + lane*16 -- all call sites arrange that.
__device__ __forceinline__ void async_load16(const void* g, void* l) {
  auto gp = (const __attribute__((address_space(1))) unsigned int*)(unsigned long long)(g);
  auto lp = (__attribute__((address_space(3))) unsigned int*)(unsigned int)(unsigned long long)(l);
  __builtin_amdgcn_global_load_lds(gp, lp, 16, 0, 0);
}

// ------------------------------------------- fp32->bf16, all 5 tensors fused
__global__ __launch_bounds__(256) void cvt_all(const float* __restrict__ x,
                                               const float* __restrict__ w0,
                                               const float* __restrict__ w1,
                                               const float* __restrict__ w2,
                                               const float* __restrict__ w3,
                                               u16* __restrict__ xo,
                                               u16* __restrict__ o0,
                                               u16* __restrict__ o1,
                                               u16* __restrict__ o2,
                                               u16* __restrict__ o3) {
  long b = blockIdx.x;
  const float* in; u16* out;
  if (b < 3456) { in = x; out = xo; }
  else {
    long wi = (b - 3456) / 4608;
    b = (b - 3456) % 4608;
    in  = (wi == 0) ? w0 : (wi == 1) ? w1 : (wi == 2) ? w2 : w3;
    out = (wi == 0) ? o0 : (wi == 1) ? o1 : (wi == 2) ? o2 : o3;
  }
  long i = (b * 256 + threadIdx.x) * 8;
  float4 a = *(const float4*)(in + i);
  float4 c = *(const float4*)(in + i + 4);
  union { u16 h[8]; uint4 u; } r;
  r.h[0] = f2bf(a.x); r.h[1] = f2bf(a.y); r.h[2] = f2bf(a.z); r.h[3] = f2bf(a.w);
  r.h[4] = f2bf(c.x); r.h[5] = f2bf(c.y); r.h[6] = f2bf(c.z); r.h[7] = f2bf(c.w);
  *(uint4*)(out + i) = r.u;
}

// ------------------------------------------------------------------- GEMM-BT
// C[M,N] = A[M,K] @ B[N,K]^T + bias.  A,B bf16; C fp32.
// 128x128 tile, BK=64, 4 waves of 64x64, 16x16x32 MFMA.
__global__ __launch_bounds__(256, 2) void gemm_bt(const u16* __restrict__ A,
                                                  const u16* __restrict__ B,
                                                  const float* __restrict__ bias,
                                                  float* __restrict__ C) {
  constexpr int N = NDIM, K = NDIM;
  __shared__ u16 As[128 * 64];
  __shared__ u16 Bs[128 * 64];
  const int t = threadIdx.x;
  const int l = t & 63, w = t >> 6;
  const int l15 = l & 15, quad = l >> 4;
  const int wm = (w >> 1) * 64, wn = (w & 1) * 64;
  const int bm = blockIdx.y * 128, bn = blockIdx.x * 128;

  floatx4 acc[4][4];
#pragma unroll
  for (int i = 0; i < 4; ++i)
#pragma unroll
    for (int j = 0; j < 4; ++j) acc[i][j] = {0.f, 0.f, 0.f, 0.f};

  for (int kt = 0; kt < K / 64; ++kt) {
    const int k0 = kt * 64;
#pragma unroll
    for (int i = 0; i < 4; ++i) {
      int p = i * 256 + t;            // chunk index 0..1023 (wave-contiguous)
      int r = p >> 3;
      int c = (p & 7) ^ (r & 7);      // fetch the chunk that lands swizzled
      async_load16(A + (long)(bm + r) * K + k0 + c * 8, As + p * 8);
      async_load16(B + (long)(bn + r) * K + k0 + c * 8, Bs + p * 8);
    }
    __syncthreads();
#pragma unroll
    for (int kk = 0; kk < 2; ++kk) {
      bf16x8 af[4], bfr[4];
#pragma unroll
      for (int i = 0; i < 4; ++i) {
        int row = wm + i * 16 + l15;
        int cc = kk * 4 + quad;
        af[i] = *(const bf16x8*)(As + (row * 8 + (cc ^ (row & 7))) * 8);
      }
#pragma unroll
      for (int j = 0; j < 4; ++j) {
        int row = wn + j * 16 + l15;
        int cc = kk * 4 + quad;
        bfr[j] = *(const bf16x8*)(Bs + (row * 8 + (cc ^ (row & 7))) * 8);
      }
#pragma unroll
      for (int i = 0; i < 4; ++i)
#pragma unroll
        for (int j = 0; j < 4; ++j)
          acc[i][j] = __builtin_amdgcn_mfma_f32_16x16x32_bf16(af[i], bfr[j], acc[i][j], 0, 0, 0);
    }
    __syncthreads();
  }
#pragma unroll
  for (int i = 0; i < 4; ++i)
#pragma unroll
    for (int j = 0; j < 4; ++j) {
      int gm = bm + wm + i * 16 + quad * 4;
      int gn = bn + wn + j * 16 + l15;
      float bv = bias[gn];
#pragma unroll
      for (int r = 0; r < 4; ++r)
        C[(long)(gm + r) * N + gn] = acc[i][j][r] + bv;
    }
}

// --------------------------------------------------- fused RMSNorm + 3D RoPE
__global__ __launch_bounds__(256) void rmsnorm_rope(const float* __restrict__ xf,
                                                    const float* __restrict__ g,
                                                    const float* __restrict__ freqs,
                                                    const int* __restrict__ gsz,
                                                    u16* __restrict__ outp) {
  const int tok = blockIdx.x;
  const int tid = threadIdx.x;
  const float* row = xf + (long)tok * NDIM;
  float4 v[3];
  float ss = 0.f;
#pragma unroll
  for (int p = 0; p < 3; ++p) {
    v[p] = ((const float4*)row)[p * 256 + tid];
    ss += v[p].x * v[p].x + v[p].y * v[p].y + v[p].z * v[p].z + v[p].w * v[p].w;
  }
#pragma unroll
  for (int m = 1; m < 64; m <<= 1) ss += __shfl_xor(ss, m);
  __shared__ float red[4];
  if ((tid & 63) == 0) red[tid >> 6] = ss;
  __syncthreads();
  ss = red[0] + red[1] + red[2] + red[3];
  const float scale = rsqrtf(ss * (1.0f / NDIM) + 1e-6f);

  const int gh = gsz[1], gw = gsz[2];
  const int hw = gh * gw;
  const int fi = tok / hw;
  const int hi = (tok % hw) / gw;
  const int wi = tok % gw;
#pragma unroll
  for (int p = 0; p < 3; ++p) {
    const int e0 = (p * 256 + tid) * 4;
    const float4 gg = ((const float4*)g)[p * 256 + tid];
    const int hh = e0 >> 7;
    const int d = e0 & 127;
    const int c0 = d >> 1;
    int pos0 = (c0 < 22) ? fi : ((c0 < 43) ? hi : wi);
    int pos1 = (c0 + 1 < 22) ? fi : ((c0 + 1 < 43) ? hi : wi);
    float th0 = freqs[pos0 * 64 + c0];
    float th1 = freqs[pos1 * 64 + c0 + 1];
    float s0, cc0, s1, cc1;
    __sincosf(th0, &s0, &cc0);
    __sincosf(th1, &s1, &cc1);
    float x0 = v[p].x * scale * gg.x;
    float x1 = v[p].y * scale * gg.y;
    float x2 = v[p].z * scale * gg.z;
    float x3 = v[p].w * scale * gg.w;
    union { u16 h[4]; uint2 u; } o;
    o.h[0] = f2bf(x0 * cc0 - x1 * s0);
    o.h[1] = f2bf(x0 * s0 + x1 * cc0);
    o.h[2] = f2bf(x2 * cc1 - x3 * s1);
    o.h[3] = f2bf(x2 * s1 + x3 * cc1);
    *(uint2*)(outp + ((long)hh * S_LEN + tok) * HD + d) = o.u;
  }
}

// ----------------------------------------------- V: [S,3072] fp32 -> [3072,S] bf16
__global__ __launch_bounds__(256) void vtrans(const float* __restrict__ vf,
                                              u16* __restrict__ vt) {
  __shared__ float tile[64][65];
  const int c0 = blockIdx.x * 64;
  const int t0 = blockIdx.y * 64;
  const int tid = threadIdx.x;
#pragma unroll
  for (int it = 0; it < 16; ++it) {
    int idx = it * 256 + tid;
    int r = idx >> 6, c = idx & 63;
    tile[r][c] = vf[(long)(t0 + r) * NDIM + c0 + c];
  }
  __syncthreads();
#pragma unroll
  for (int it = 0; it < 16; ++it) {
    int idx = it * 256 + tid;
    int r = idx >> 6, c = idx & 63;
    vt[(long)(c0 + r) * S_LEN + t0 + c] = f2bf(tile[c][r]);
  }
}

// ------------------------------------------------------------ flash attention
// qb,kb: bf16 [NH][S][HD]; vt: bf16 [NH*HD][S]; out: bf16 [S][3072].
// 216 blocks x 512 threads (8 waves, 32 q-rows each -> Q-tile 256).
// Halves K/V re-fetch vs 128-row tiles: 9 passes/head instead of 18.
// LDS 64 KB: KPs (32 KB) holds the K tile, then P in two 64-col halves
// (P-half = 256x64 bf16 = 32 KB, wave-private rows). Vs 32 KB. 2 blocks/CU.
// XCD swizzle: b&7 -> xcd, 27 slots = 3 heads x 9 qtiles per XCD.
__global__ __launch_bounds__(512, 4) void attn_kern(const u16* __restrict__ qb,
                                                    const u16* __restrict__ kb,
                                                    const u16* __restrict__ vt,
                                                    const int* __restrict__ seq_lens,
                                                    u16* __restrict__ ob) {
  __shared__ u16 KPs[16384];   // K tile [128r x 16ch] OR P half [256r x 8ch]
  __shared__ u16 Vs[16384];    // V^T tile [128d x 16ch]
  const int b = blockIdx.x;           // 0..215
  const int xcd = b & 7;
  const int slot = b >> 3;            // 0..26
  const int h = xcd * 3 + slot / 9;   // 3 heads per XCD
  const int qt = slot % 9;
  const int t = threadIdx.x;
  const int l = t & 63, w = t >> 6;   // 8 waves
  const int l15 = l & 15, quad = l >> 4;
  const int seqlen = seq_lens[0];
  const float SC = 0.08838834764831845f;  // 1/sqrt(128)

  // Q fragments: A-layout m = lane&15, k = quad*8 + j
  bf16x8 qfrag[2][4];
#pragma unroll
  for (int i = 0; i < 2; ++i) {
    const u16* qrow = qb + ((long)h * S_LEN + qt * 256 + w * 32 + i * 16 + l15) * HD + quad * 8;
#pragma unroll
    for (int kk = 0; kk < 4; ++kk) qfrag[i][kk] = *(const bf16x8*)(qrow + kk * 32);
  }

  floatx4 oacc[2][8];
  float mrow[2][4], lrow[2][4];
#pragma unroll
  for (int i = 0; i < 2; ++i) {
#pragma unroll
    for (int j = 0; j < 8; ++j) oacc[i][j] = {0.f, 0.f, 0.f, 0.f};
#pragma unroll
    for (int r = 0; r < 4; ++r) { mrow[i][r] = -1e30f; lrow[i][r] = 0.f; }
  }

  for (int kt = 0; kt < S_LEN / 128; ++kt) {
    // stage K [tok][hd] and V^T [hd][tok] tiles, swizzle mask 15
#pragma unroll
    for (int i = 0; i < 4; ++i) {
      int p = i * 512 + t;            // 0..2047
      int r = p >> 4;
      int c = (p & 15) ^ (r & 15);
      async_load16(kb + ((long)h * S_LEN + kt * 128 + r) * HD + c * 8, KPs + p * 8);
      async_load16(vt + ((long)(h * HD) + r) * S_LEN + kt * 128 + c * 8, Vs + p * 8);
    }
    __syncthreads();

    // S = Q K^T
    floatx4 sacc[2][8];
#pragma unroll
    for (int i = 0; i < 2; ++i)
#pragma unroll
      for (int j = 0; j < 8; ++j) sacc[i][j] = {0.f, 0.f, 0.f, 0.f};
#pragma unroll
    for (int kk = 0; kk < 4; ++kk) {
#pragma unroll
      for (int j = 0; j < 8; ++j) {
        int row = j * 16 + l15;
        int cc = kk * 4 + quad;
        bf16x8 bk = *(const bf16x8*)(KPs + (row * 16 + (cc ^ (row & 15))) * 8);
        sacc[0][j] = __builtin_amdgcn_mfma_f32_16x16x32_bf16(qfrag[0][kk], bk, sacc[0][j], 0, 0, 0);
        sacc[1][j] = __builtin_amdgcn_mfma_f32_16x16x32_bf16(qfrag[1][kk], bk, sacc[1][j], 0, 0, 0);
      }
    }

    // online softmax (each wave owns its 32 q-rows fully)
#pragma unroll
    for (int i = 0; i < 2; ++i) {
      if (kt * 128 + 128 > seqlen) {
#pragma unroll
        for (int j = 0; j < 8; ++j)
#pragma unroll
          for (int r = 0; r < 4; ++r) {
            int col = kt * 128 + j * 16 + l15;
            sacc[i][j][r] = (col >= seqlen) ? -1e30f : sacc[i][j][r] * SC;
          }
      } else {
#pragma unroll
        for (int j = 0; j < 8; ++j)
#pragma unroll
          for (int r = 0; r < 4; ++r) sacc[i][j][r] *= SC;
      }
      float mnew[4], alpha[4];
#pragma unroll
      for (int r = 0; r < 4; ++r) {
        float m = sacc[i][0][r];
#pragma unroll
        for (int j = 1; j < 8; ++j) m = fmaxf(m, sacc[i][j][r]);
        m = fmaxf(m, __shfl_xor(m, 1));
        m = fmaxf(m, __shfl_xor(m, 2));
        m = fmaxf(m, __shfl_xor(m, 4));
        m = fmaxf(m, __shfl_xor(m, 8));
        mnew[r] = fmaxf(mrow[i][r], m);
        alpha[r] = __expf(mrow[i][r] - mnew[r]);
        mrow[i][r] = mnew[r];
      }
#pragma unroll
      for (int j = 0; j < 8; ++j)
#pragma unroll
        for (int r = 0; r < 4; ++r) sacc[i][j][r] = __expf(sacc[i][j][r] - mnew[r]);
#pragma unroll
      for (int r = 0; r < 4; ++r) {
        float s = 0.f;
#pragma unroll
        for (int j = 0; j < 8; ++j) s += sacc[i][j][r];
        s += __shfl_xor(s, 1);
        s += __shfl_xor(s, 2);
        s += __shfl_xor(s, 4);
        s += __shfl_xor(s, 8);
        lrow[i][r] = lrow[i][r] * alpha[r] + s;
      }
#pragma unroll
      for (int j = 0; j < 8; ++j)
#pragma unroll
        for (int r = 0; r < 4; ++r) oacc[i][j][r] *= alpha[r];
    }

    __syncthreads();  // all waves done reading K before P overwrites KPs

    // P -> LDS -> PV in two 64-col halves (wave-private rows, no barrier)
#pragma unroll
    for (int half = 0; half < 2; ++half) {
      // write P cols [half*64, half*64+64) ; layout [256r x 8ch] xor-swizzled
#pragma unroll
      for (int i = 0; i < 2; ++i)
#pragma unroll
        for (int jj = 0; jj < 4; ++jj) {
          int j = half * 4 + jj;
#pragma unroll
          for (int r = 0; r < 4; ++r) {
            int rq = w * 32 + i * 16 + quad * 4 + r;   // 0..255
            int ct = jj * 16 + l15;                    // 0..63 local col
            int cc = ct >> 3;
            KPs[(rq * 8 + (cc ^ (rq & 7))) * 8 + (ct & 7)] = f2bf(sacc[i][j][r]);
          }
        }
      // O += P_half @ V_half
#pragma unroll
      for (int kl = 0; kl < 2; ++kl) {
        bf16x8 ap[2];
#pragma unroll
        for (int i = 0; i < 2; ++i) {
          int row = w * 32 + i * 16 + l15;
          int cc = kl * 4 + quad;                      // local chunk 0..7
          ap[i] = *(const bf16x8*)(KPs + (row * 8 + (cc ^ (row & 7))) * 8);
        }
        int kkg = half * 2 + kl;
#pragma unroll
        for (int j = 0; j < 8; ++j) {
          int rowv = j * 16 + l15;
          int ccv = kkg * 4 + quad;
          bf16x8 bv = *(const bf16x8*)(Vs + (rowv * 16 + (ccv ^ (rowv & 15))) * 8);
          oacc[0][j] = __builtin_amdgcn_mfma_f32_16x16x32_bf16(ap[0], bv, oacc[0][j], 0, 0, 0);
          oacc[1][j] = __builtin_amdgcn_mfma_f32_16x16x32_bf16(ap[1], bv, oacc[1][j], 0, 0, 0);
        }
      }
    }
    __syncthreads();  // before next stage overwrites KPs/Vs
  }

  // epilogue: out[t][h*128+d] = O / l
#pragma unroll
  for (int i = 0; i < 2; ++i)
#pragma unroll
    for (int j = 0; j < 8; ++j) {
      int gt = qt * 256 + w * 32 + i * 16 + quad * 4;
      int gc = h * HD + j * 16 + l15;
#pragma unroll
      for (int r = 0; r < 4; ++r)
        ob[(long)(gt + r) * NDIM + gc] = f2bf(oacc[i][j][r] / lrow[i][r]);
    }
}

// ----------------------------------------------------------------------------
extern "C" void kernel_launch(void* const* d_in, const int* in_sizes, int n_in,
                              void* d_out, int out_size, void* d_ws, size_t ws_size,
                              hipStream_t stream) {
  const float* x        = (const float*)d_in[0];
  const int*   seq_lens = (const int*)  d_in[1];
  const int*   gsz      = (const int*)  d_in[2];
  const float* freqs    = (const float*)d_in[3];
  const float* wq       = (const float*)d_in[4];
  const float* bq       = (const float*)d_in[5];
  const float* wk       = (const float*)d_in[6];
  const float* bk       = (const float*)d_in[7];
  const float* wv       = (const float*)d_in[8];
  const float* bv       = (const float*)d_in[9];
  const float* wo       = (const float*)d_in[10];
  const float* bo       = (const float*)d_in[11];
  const float* gq       = (const float*)d_in[12];
  const float* gk       = (const float*)d_in[13];
  float* out = (float*)d_out;

  char* ws = (char*)d_ws;
  const size_t SD2 = (size_t)S_LEN * NDIM * 2;   // bf16 [S,3072]
  const size_t W2  = (size_t)NDIM * NDIM * 2;    // bf16 [3072,3072]
  const size_t SD4 = (size_t)S_LEN * NDIM * 4;   // fp32 [S,3072]
  size_t off = 0;
  u16* xb    = (u16*)(ws + off); off += SD2;
  u16* wqb   = (u16*)(ws + off); off += W2;
  u16* wkb   = (u16*)(ws + off); off += W2;
  u16* wvb   = (u16*)(ws + off); off += W2;
  u16* wob   = (u16*)(ws + off); off += W2;
  float* qf  = (float*)(ws + off); off += SD4;
  float* kf  = (float*)(ws + off); off += SD4;
  float* vf  = (float*)(ws + off); off += SD4;
  u16* qbuf  = (u16*)(ws + off); off += SD2;
  u16* kbuf  = (u16*)(ws + off); off += SD2;
  u16* vtb   = (u16*)(ws + off); off += SD2;
  u16* attnb = (u16*)(ws + off); off += SD2;

  cvt_all<<<3456 + 4 * 4608, 256, 0, stream>>>(x, wq, wk, wv, wo,
                                               xb, wqb, wkb, wvb, wob);

  dim3 gg(NDIM / 128, S_LEN / 128);
  gemm_bt<<<gg, 256, 0, stream>>>(xb, wqb, bq, qf);
  gemm_bt<<<gg, 256, 0, stream>>>(xb, wkb, bk, kf);
  gemm_bt<<<gg, 256, 0, stream>>>(xb, wvb, bv, vf);

  rmsnorm_rope<<<S_LEN, 256, 0, stream>>>(qf, gq, freqs, gsz, qbuf);
  rmsnorm_rope<<<S_LEN, 256, 0, stream>>>(kf, gk, freqs, gsz, kbuf);
  vtrans<<<dim3(NDIM / 64, S_LEN / 64), 256, 0, stream>>>(vf, vtb);

  attn_kern<<<216, 512, 0, stream>>>(qbuf, kbuf, vtb, seq_lens, attnb);

  gemm_bt<<<gg, 256, 0, stream>>>(attnb, wob, bo, out);
}

// Round 4
// 610.550 us; speedup vs baseline: 1.8161x; 1.8161x over previous
//
#include <hip/hip_runtime.h>
#include <hip/hip_bf16.h>
#include <cstdint>

#define S_LEN 2304
#define NDIM  3072
#define NH    24
#define HD    128

typedef unsigned short u16;
typedef __bf16  bf16x8  __attribute__((ext_vector_type(8)));
typedef float   floatx4 __attribute__((ext_vector_type(4)));

__device__ __forceinline__ u16 f2bf(float x) {
  union { float f; unsigned int u; } a; a.f = x;
  unsigned int r = (a.u + 0x7FFFu + ((a.u >> 16) & 1u)) >> 16;
  return (u16)r;
}

// async 16B global->LDS (direct-to-shared DMA). LDS dest must be
// wave-uniform base + lane*16 -- all call sites arrange that.
__device__ __forceinline__ void async_load16(const void* g, void* l) {
  auto gp = (const __attribute__((address_space(1))) unsigned int*)(unsigned long long)(g);
  auto lp = (__attribute__((address_space(3))) unsigned int*)(unsigned int)(unsigned long long)(l);
  __builtin_amdgcn_global_load_lds(gp, lp, 16, 0, 0);
}

// ------------------------------------------- fp32->bf16, all 5 tensors fused
__global__ __launch_bounds__(256) void cvt_all(const float* __restrict__ x,
                                               const float* __restrict__ w0,
                                               const float* __restrict__ w1,
                                               const float* __restrict__ w2,
                                               const float* __restrict__ w3,
                                               u16* __restrict__ xo,
                                               u16* __restrict__ o0,
                                               u16* __restrict__ o1,
                                               u16* __restrict__ o2,
                                               u16* __restrict__ o3) {
  long b = blockIdx.x;
  const float* in; u16* out;
  if (b < 3456) { in = x; out = xo; }
  else {
    long wi = (b - 3456) / 4608;
    b = (b - 3456) % 4608;
    in  = (wi == 0) ? w0 : (wi == 1) ? w1 : (wi == 2) ? w2 : w3;
    out = (wi == 0) ? o0 : (wi == 1) ? o1 : (wi == 2) ? o2 : o3;
  }
  long i = (b * 256 + threadIdx.x) * 8;
  float4 a = *(const float4*)(in + i);
  float4 c = *(const float4*)(in + i + 4);
  union { u16 h[8]; uint4 u; } r;
  r.h[0] = f2bf(a.x); r.h[1] = f2bf(a.y); r.h[2] = f2bf(a.z); r.h[3] = f2bf(a.w);
  r.h[4] = f2bf(c.x); r.h[5] = f2bf(c.y); r.h[6] = f2bf(c.z); r.h[7] = f2bf(c.w);
  *(uint4*)(out + i) = r.u;
}

// ------------------------------------------------------------------- GEMM-BT
// C[M,N] = A[M,K] @ B[N,K]^T + bias.  A,B bf16; C fp32.
// 128x128 tile, BK=64, 4 waves of 64x64, 16x16x32 MFMA.
__global__ __launch_bounds__(256, 2) void gemm_bt(const u16* __restrict__ A,
                                                  const u16* __restrict__ B,
                                                  const float* __restrict__ bias,
                                                  float* __restrict__ C) {
  constexpr int N = NDIM, K = NDIM;
  __shared__ u16 As[128 * 64];
  __shared__ u16 Bs[128 * 64];
  const int t = threadIdx.x;
  const int l = t & 63, w = t >> 6;
  const int l15 = l & 15, quad = l >> 4;
  const int wm = (w >> 1) * 64, wn = (w & 1) * 64;
  const int bm = blockIdx.y * 128, bn = blockIdx.x * 128;

  floatx4 acc[4][4];
#pragma unroll
  for (int i = 0; i < 4; ++i)
#pragma unroll
    for (int j = 0; j < 4; ++j) acc[i][j] = {0.f, 0.f, 0.f, 0.f};

  for (int kt = 0; kt < K / 64; ++kt) {
    const int k0 = kt * 64;
#pragma unroll
    for (int i = 0; i < 4; ++i) {
      int p = i * 256 + t;            // chunk index 0..1023 (wave-contiguous)
      int r = p >> 3;
      int c = (p & 7) ^ (r & 7);      // fetch the chunk that lands swizzled
      async_load16(A + (long)(bm + r) * K + k0 + c * 8, As + p * 8);
      async_load16(B + (long)(bn + r) * K + k0 + c * 8, Bs + p * 8);
    }
    __syncthreads();
#pragma unroll
    for (int kk = 0; kk < 2; ++kk) {
      bf16x8 af[4], bfr[4];
#pragma unroll
      for (int i = 0; i < 4; ++i) {
        int row = wm + i * 16 + l15;
        int cc = kk * 4 + quad;
        af[i] = *(const bf16x8*)(As + (row * 8 + (cc ^ (row & 7))) * 8);
      }
#pragma unroll
      for (int j = 0; j < 4; ++j) {
        int row = wn + j * 16 + l15;
        int cc = kk * 4 + quad;
        bfr[j] = *(const bf16x8*)(Bs + (row * 8 + (cc ^ (row & 7))) * 8);
      }
#pragma unroll
      for (int i = 0; i < 4; ++i)
#pragma unroll
        for (int j = 0; j < 4; ++j)
          acc[i][j] = __builtin_amdgcn_mfma_f32_16x16x32_bf16(af[i], bfr[j], acc[i][j], 0, 0, 0);
    }
    __syncthreads();
  }
#pragma unroll
  for (int i = 0; i < 4; ++i)
#pragma unroll
    for (int j = 0; j < 4; ++j) {
      int gm = bm + wm + i * 16 + quad * 4;
      int gn = bn + wn + j * 16 + l15;
      float bv = bias[gn];
#pragma unroll
      for (int r = 0; r < 4; ++r)
        C[(long)(gm + r) * N + gn] = acc[i][j][r] + bv;
    }
}

// --------------------------------------------------- fused RMSNorm + 3D RoPE
__global__ __launch_bounds__(256) void rmsnorm_rope(const float* __restrict__ xf,
                                                    const float* __restrict__ g,
                                                    const float* __restrict__ freqs,
                                                    const int* __restrict__ gsz,
                                                    u16* __restrict__ outp) {
  const int tok = blockIdx.x;
  const int tid = threadIdx.x;
  const float* row = xf + (long)tok * NDIM;
  float4 v[3];
  float ss = 0.f;
#pragma unroll
  for (int p = 0; p < 3; ++p) {
    v[p] = ((const float4*)row)[p * 256 + tid];
    ss += v[p].x * v[p].x + v[p].y * v[p].y + v[p].z * v[p].z + v[p].w * v[p].w;
  }
#pragma unroll
  for (int m = 1; m < 64; m <<= 1) ss += __shfl_xor(ss, m);
  __shared__ float red[4];
  if ((tid & 63) == 0) red[tid >> 6] = ss;
  __syncthreads();
  ss = red[0] + red[1] + red[2] + red[3];
  const float scale = rsqrtf(ss * (1.0f / NDIM) + 1e-6f);

  const int gh = gsz[1], gw = gsz[2];
  const int hw = gh * gw;
  const int fi = tok / hw;
  const int hi = (tok % hw) / gw;
  const int wi = tok % gw;
#pragma unroll
  for (int p = 0; p < 3; ++p) {
    const int e0 = (p * 256 + tid) * 4;
    const float4 gg = ((const float4*)g)[p * 256 + tid];
    const int hh = e0 >> 7;
    const int d = e0 & 127;
    const int c0 = d >> 1;
    int pos0 = (c0 < 22) ? fi : ((c0 < 43) ? hi : wi);
    int pos1 = (c0 + 1 < 22) ? fi : ((c0 + 1 < 43) ? hi : wi);
    float th0 = freqs[pos0 * 64 + c0];
    float th1 = freqs[pos1 * 64 + c0 + 1];
    float s0, cc0, s1, cc1;
    __sincosf(th0, &s0, &cc0);
    __sincosf(th1, &s1, &cc1);
    float x0 = v[p].x * scale * gg.x;
    float x1 = v[p].y * scale * gg.y;
    float x2 = v[p].z * scale * gg.z;
    float x3 = v[p].w * scale * gg.w;
    union { u16 h[4]; uint2 u; } o;
    o.h[0] = f2bf(x0 * cc0 - x1 * s0);
    o.h[1] = f2bf(x0 * s0 + x1 * cc0);
    o.h[2] = f2bf(x2 * cc1 - x3 * s1);
    o.h[3] = f2bf(x2 * s1 + x3 * cc1);
    *(uint2*)(outp + ((long)hh * S_LEN + tok) * HD + d) = o.u;
  }
}

// ----------------------------------------------- V: [S,3072] fp32 -> [3072,S] bf16
__global__ __launch_bounds__(256) void vtrans(const float* __restrict__ vf,
                                              u16* __restrict__ vt) {
  __shared__ float tile[64][65];
  const int c0 = blockIdx.x * 64;
  const int t0 = blockIdx.y * 64;
  const int tid = threadIdx.x;
#pragma unroll
  for (int it = 0; it < 16; ++it) {
    int idx = it * 256 + tid;
    int r = idx >> 6, c = idx & 63;
    tile[r][c] = vf[(long)(t0 + r) * NDIM + c0 + c];
  }
  __syncthreads();
#pragma unroll
  for (int it = 0; it < 16; ++it) {
    int idx = it * 256 + tid;
    int r = idx >> 6, c = idx & 63;
    vt[(long)(c0 + r) * S_LEN + t0 + c] = f2bf(tile[c][r]);
  }
}

// ------------------------------------------------------------ flash attention
// qb,kb: bf16 [NH][S][HD]; vt: bf16 [NH*HD][S]; out: bf16 [S][3072].
// 432 blocks x 256 threads (4 waves x 32 q-rows, Q-tile 128). K-tile = 64
// tokens, DOUBLE-BUFFERED: prefetch of tile kt+1 is issued right after the
// top-of-loop barrier, so the whole compute phase (QK^T, softmax, P, PV)
// runs in the shadow of the global_load_lds latency; the next barrier's
// vmcnt(0) drain then finds the loads already complete. P has its own LDS
// buffer (wave-private rows -> NO mid-iteration barrier). LDS = 2*16(K) +
// 2*16(V) + 16(P) = 80 KB -> 2 blocks/CU.
// XCD swizzle: b&7 -> xcd, 54 slots = 3 heads x 18 qtiles per XCD (3.5 MB
// K+V working set fits the 4 MB per-XCD L2).
__global__ __launch_bounds__(256, 2) void attn_kern(const u16* __restrict__ qb,
                                                    const u16* __restrict__ kb,
                                                    const u16* __restrict__ vt,
                                                    const int* __restrict__ seq_lens,
                                                    u16* __restrict__ ob) {
  __shared__ u16 Kb[2][64 * 128];   // K tile: 64 tok rows x 16 chunks, swz 15
  __shared__ u16 Vb[2][128 * 64];   // V^T tile: 128 d rows x 8 chunks, swz 7
  __shared__ u16 Ps[128 * 64];      // P tile: 128 q rows x 8 chunks, swz 7
  const int b = blockIdx.x;           // 0..431
  const int xcd = b & 7;
  const int slot = b >> 3;            // 0..53
  const int h = xcd * 3 + slot / 18;  // 3 heads per XCD
  const int qt = slot % 18;
  const int t = threadIdx.x;
  const int l = t & 63, w = t >> 6;
  const int l15 = l & 15, quad = l >> 4;
  const int seqlen = seq_lens[0];
  const float SC = 0.08838834764831845f;  // 1/sqrt(128)

  const u16* kbase = kb + (long)h * S_LEN * HD;
  const u16* vbase = vt + (long)h * HD * S_LEN;

  // Q fragments: A-layout m = lane&15, k = quad*8 + j
  bf16x8 qfrag[2][4];
#pragma unroll
  for (int i = 0; i < 2; ++i) {
    const u16* qrow = qb + ((long)h * S_LEN + qt * 128 + w * 32 + i * 16 + l15) * HD + quad * 8;
#pragma unroll
    for (int kk = 0; kk < 4; ++kk) qfrag[i][kk] = *(const bf16x8*)(qrow + kk * 32);
  }

  floatx4 oacc[2][8];
  float mrow[2][4], lrow[2][4];
#pragma unroll
  for (int i = 0; i < 2; ++i) {
#pragma unroll
    for (int j = 0; j < 8; ++j) oacc[i][j] = {0.f, 0.f, 0.f, 0.f};
#pragma unroll
    for (int r = 0; r < 4; ++r) { mrow[i][r] = -1e30f; lrow[i][r] = 0.f; }
  }

  // stage K-tile (64x128) + V-tile (128x64) for tile `kt` into buffer `buf`
  auto stage = [&](int kt, int buf) {
#pragma unroll
    for (int i = 0; i < 4; ++i) {
      int p = i * 256 + t;              // 0..1023
      int rk = p >> 4;                  // K: token row 0..63
      int ck = (p & 15) ^ (rk & 15);    // chunk whose content lands at slot p&15
      async_load16(kbase + ((long)(kt * 64 + rk)) * HD + ck * 8, &Kb[buf][p * 8]);
      int dv = p >> 3;                  // V: hd row 0..127
      int cv = (p & 7) ^ (dv & 7);
      async_load16(vbase + (long)dv * S_LEN + kt * 64 + cv * 8, &Vb[buf][p * 8]);
    }
  };

  stage(0, 0);

  for (int kt = 0; kt < S_LEN / 64; ++kt) {
    const int cur = kt & 1;
    __syncthreads();                   // tile kt loads done; prev compute done
    if (kt + 1 < S_LEN / 64) stage(kt + 1, cur ^ 1);

    // S = Q K^T  (128q x 64k)
    floatx4 sacc[2][4];
#pragma unroll
    for (int i = 0; i < 2; ++i)
#pragma unroll
      for (int j = 0; j < 4; ++j) sacc[i][j] = {0.f, 0.f, 0.f, 0.f};
#pragma unroll
    for (int kk = 0; kk < 4; ++kk) {
#pragma unroll
      for (int j = 0; j < 4; ++j) {
        int row = j * 16 + l15;
        int cc = kk * 4 + quad;
        bf16x8 bk = *(const bf16x8*)(&Kb[cur][(row * 16 + (cc ^ (row & 15))) * 8]);
        sacc[0][j] = __builtin_amdgcn_mfma_f32_16x16x32_bf16(qfrag[0][kk], bk, sacc[0][j], 0, 0, 0);
        sacc[1][j] = __builtin_amdgcn_mfma_f32_16x16x32_bf16(qfrag[1][kk], bk, sacc[1][j], 0, 0, 0);
      }
    }

    // online softmax (each wave owns its 32 q-rows fully)
#pragma unroll
    for (int i = 0; i < 2; ++i) {
      if (kt * 64 + 64 > seqlen) {
#pragma unroll
        for (int j = 0; j < 4; ++j)
#pragma unroll
          for (int r = 0; r < 4; ++r) {
            int col = kt * 64 + j * 16 + l15;
            sacc[i][j][r] = (col >= seqlen) ? -1e30f : sacc[i][j][r] * SC;
          }
      } else {
#pragma unroll
        for (int j = 0; j < 4; ++j)
#pragma unroll
          for (int r = 0; r < 4; ++r) sacc[i][j][r] *= SC;
      }
      float mnew[4], alpha[4];
#pragma unroll
      for (int r = 0; r < 4; ++r) {
        float m = sacc[i][0][r];
#pragma unroll
        for (int j = 1; j < 4; ++j) m = fmaxf(m, sacc[i][j][r]);
        m = fmaxf(m, __shfl_xor(m, 1));
        m = fmaxf(m, __shfl_xor(m, 2));
        m = fmaxf(m, __shfl_xor(m, 4));
        m = fmaxf(m, __shfl_xor(m, 8));
        mnew[r] = fmaxf(mrow[i][r], m);
        alpha[r] = __expf(mrow[i][r] - mnew[r]);
        mrow[i][r] = mnew[r];
      }
#pragma unroll
      for (int j = 0; j < 4; ++j)
#pragma unroll
        for (int r = 0; r < 4; ++r) sacc[i][j][r] = __expf(sacc[i][j][r] - mnew[r]);
#pragma unroll
      for (int r = 0; r < 4; ++r) {
        float s = 0.f;
#pragma unroll
        for (int j = 0; j < 4; ++j) s += sacc[i][j][r];
        s += __shfl_xor(s, 1);
        s += __shfl_xor(s, 2);
        s += __shfl_xor(s, 4);
        s += __shfl_xor(s, 8);
        lrow[i][r] = lrow[i][r] * alpha[r] + s;
      }
#pragma unroll
      for (int j = 0; j < 8; ++j)
#pragma unroll
        for (int r = 0; r < 4; ++r) oacc[i][j][r] *= alpha[r];
    }

    // write P into its own buffer (wave-private rows -> no barrier)
#pragma unroll
    for (int i = 0; i < 2; ++i)
#pragma unroll
      for (int j = 0; j < 4; ++j)
#pragma unroll
        for (int r = 0; r < 4; ++r) {
          int rq = w * 32 + i * 16 + quad * 4 + r;   // 0..127
          int ct = j * 16 + l15;                     // 0..63
          int cc = ct >> 3;
          Ps[(rq * 8 + (cc ^ (rq & 7))) * 8 + (ct & 7)] = f2bf(sacc[i][j][r]);
        }

    // O += P V   (A-frags: own rows of Ps; B: V^T rows = output dims)
#pragma unroll
    for (int kl = 0; kl < 2; ++kl) {
      bf16x8 ap[2];
#pragma unroll
      for (int i = 0; i < 2; ++i) {
        int row = w * 32 + i * 16 + l15;
        int cc = kl * 4 + quad;
        ap[i] = *(const bf16x8*)(&Ps[(row * 8 + (cc ^ (row & 7))) * 8]);
      }
#pragma unroll
      for (int j = 0; j < 8; ++j) {
        int d = j * 16 + l15;
        int ccv = kl * 4 + quad;
        bf16x8 bv = *(const bf16x8*)(&Vb[cur][(d * 8 + (ccv ^ (d & 7))) * 8]);
        oacc[0][j] = __builtin_amdgcn_mfma_f32_16x16x32_bf16(ap[0], bv, oacc[0][j], 0, 0, 0);
        oacc[1][j] = __builtin_amdgcn_mfma_f32_16x16x32_bf16(ap[1], bv, oacc[1][j], 0, 0, 0);
      }
    }
  }

  // epilogue: out[t][h*128+d] = O / l
#pragma unroll
  for (int i = 0; i < 2; ++i)
#pragma unroll
    for (int j = 0; j < 8; ++j) {
      int gt = qt * 128 + w * 32 + i * 16 + quad * 4;
      int gc = h * HD + j * 16 + l15;
#pragma unroll
      for (int r = 0; r < 4; ++r)
        ob[(long)(gt + r) * NDIM + gc] = f2bf(oacc[i][j][r] / lrow[i][r]);
    }
}

// ----------------------------------------------------------------------------
extern "C" void kernel_launch(void* const* d_in, const int* in_sizes, int n_in,
                              void* d_out, int out_size, void* d_ws, size_t ws_size,
                              hipStream_t stream) {
  const float* x        = (const float*)d_in[0];
  const int*   seq_lens = (const int*)  d_in[1];
  const int*   gsz      = (const int*)  d_in[2];
  const float* freqs    = (const float*)d_in[3];
  const float* wq       = (const float*)d_in[4];
  const float* bq       = (const float*)d_in[5];
  const float* wk       = (const float*)d_in[6];
  const float* bk       = (const float*)d_in[7];
  const float* wv       = (const float*)d_in[8];
  const float* bv       = (const float*)d_in[9];
  const float* wo       = (const float*)d_in[10];
  const float* bo       = (const float*)d_in[11];
  const float* gq       = (const float*)d_in[12];
  const float* gk       = (const float*)d_in[13];
  float* out = (float*)d_out;

  char* ws = (char*)d_ws;
  const size_t SD2 = (size_t)S_LEN * NDIM * 2;   // bf16 [S,3072]
  const size_t W2  = (size_t)NDIM * NDIM * 2;    // bf16 [3072,3072]
  const size_t SD4 = (size_t)S_LEN * NDIM * 4;   // fp32 [S,3072]
  size_t off = 0;
  u16* xb    = (u16*)(ws + off); off += SD2;
  u16* wqb   = (u16*)(ws + off); off += W2;
  u16* wkb   = (u16*)(ws + off); off += W2;
  u16* wvb   = (u16*)(ws + off); off += W2;
  u16* wob   = (u16*)(ws + off); off += W2;
  float* qf  = (float*)(ws + off); off += SD4;
  float* kf  = (float*)(ws + off); off += SD4;
  float* vf  = (float*)(ws + off); off += SD4;
  u16* qbuf  = (u16*)(ws + off); off += SD2;
  u16* kbuf  = (u16*)(ws + off); off += SD2;
  u16* vtb   = (u16*)(ws + off); off += SD2;
  u16* attnb = (u16*)(ws + off); off += SD2;

  cvt_all<<<3456 + 4 * 4608, 256, 0, stream>>>(x, wq, wk, wv, wo,
                                               xb, wqb, wkb, wvb, wob);

  dim3 gg(NDIM / 128, S_LEN / 128);
  gemm_bt<<<gg, 256, 0, stream>>>(xb, wqb, bq, qf);
  gemm_bt<<<gg, 256, 0, stream>>>(xb, wkb, bk, kf);
  gemm_bt<<<gg, 256, 0, stream>>>(xb, wvb, bv, vf);

  rmsnorm_rope<<<S_LEN, 256, 0, stream>>>(qf, gq, freqs, gsz, qbuf);
  rmsnorm_rope<<<S_LEN, 256, 0, stream>>>(kf, gk, freqs, gsz, kbuf);
  vtrans<<<dim3(NDIM / 64, S_LEN / 64), 256, 0, stream>>>(vf, vtb);

  attn_kern<<<432, 256, 0, stream>>>(qbuf, kbuf, vtb, seq_lens, attnb);

  gemm_bt<<<gg, 256, 0, stream>>>(attnb, wob, bo, out);
}

// Round 5
// 568.007 us; speedup vs baseline: 1.9521x; 1.0749x over previous
//
#include <hip/hip_runtime.h>
#include <hip/hip_bf16.h>
#include <cstdint>

#define S_LEN 2304
#define NDIM  3072
#define NH    24
#define HD    128

typedef unsigned short u16;
typedef __bf16  bf16x8  __attribute__((ext_vector_type(8)));
typedef float   floatx4 __attribute__((ext_vector_type(4)));

__device__ __forceinline__ u16 f2bf(float x) {
  union { float f; unsigned int u; } a; a.f = x;
  unsigned int r = (a.u + 0x7FFFu + ((a.u >> 16) & 1u)) >> 16;
  return (u16)r;
}

// async 16B global->LDS (direct-to-shared DMA). LDS dest must be
// wave-uniform base + lane*16 -- all call sites arrange that.
__device__ __forceinline__ void async_load16(const void* g, void* l) {
  auto gp = (const __attribute__((address_space(1))) unsigned int*)(unsigned long long)(g);
  auto lp = (__attribute__((address_space(3))) unsigned int*)(unsigned int)(unsigned long long)(l);
  __builtin_amdgcn_global_load_lds(gp, lp, 16, 0, 0);
}

// ------------------------------------------- fp32->bf16, all 5 tensors fused
__global__ __launch_bounds__(256) void cvt_all(const float* __restrict__ x,
                                               const float* __restrict__ w0,
                                               const float* __restrict__ w1,
                                               const float* __restrict__ w2,
                                               const float* __restrict__ w3,
                                               u16* __restrict__ xo,
                                               u16* __restrict__ o0,
                                               u16* __restrict__ o1,
                                               u16* __restrict__ o2,
                                               u16* __restrict__ o3) {
  long b = blockIdx.x;
  const float* in; u16* out;
  if (b < 3456) { in = x; out = xo; }
  else {
    long wi = (b - 3456) / 4608;
    b = (b - 3456) % 4608;
    in  = (wi == 0) ? w0 : (wi == 1) ? w1 : (wi == 2) ? w2 : w3;
    out = (wi == 0) ? o0 : (wi == 1) ? o1 : (wi == 2) ? o2 : o3;
  }
  long i = (b * 256 + threadIdx.x) * 8;
  float4 a = *(const float4*)(in + i);
  float4 c = *(const float4*)(in + i + 4);
  union { u16 h[8]; uint4 u; } r;
  r.h[0] = f2bf(a.x); r.h[1] = f2bf(a.y); r.h[2] = f2bf(a.z); r.h[3] = f2bf(a.w);
  r.h[4] = f2bf(c.x); r.h[5] = f2bf(c.y); r.h[6] = f2bf(c.z); r.h[7] = f2bf(c.w);
  *(uint4*)(out + i) = r.u;
}

// ---------------------------------------------------------------- GEMM cores
// C[M,N] = A[M,K] @ B[N,K]^T + bias.  A,B bf16; C fp32.
// 128x128 tile, BK=64, 4 waves of 64x64, 16x16x32 MFMA.
__device__ __forceinline__ void gemm_tile(const u16* __restrict__ A,
                                          const u16* __restrict__ B,
                                          const float* __restrict__ bias,
                                          float* __restrict__ C,
                                          int bm, int bn,
                                          u16* As, u16* Bs) {
  constexpr int N = NDIM, K = NDIM;
  const int t = threadIdx.x;
  const int l = t & 63, w = t >> 6;
  const int l15 = l & 15, quad = l >> 4;
  const int wm = (w >> 1) * 64, wn = (w & 1) * 64;

  floatx4 acc[4][4];
#pragma unroll
  for (int i = 0; i < 4; ++i)
#pragma unroll
    for (int j = 0; j < 4; ++j) acc[i][j] = {0.f, 0.f, 0.f, 0.f};

  for (int kt = 0; kt < K / 64; ++kt) {
    const int k0 = kt * 64;
#pragma unroll
    for (int i = 0; i < 4; ++i) {
      int p = i * 256 + t;            // chunk index 0..1023 (wave-contiguous)
      int r = p >> 3;
      int c = (p & 7) ^ (r & 7);      // fetch the chunk that lands swizzled
      async_load16(A + (long)(bm + r) * K + k0 + c * 8, As + p * 8);
      async_load16(B + (long)(bn + r) * K + k0 + c * 8, Bs + p * 8);
    }
    __syncthreads();
#pragma unroll
    for (int kk = 0; kk < 2; ++kk) {
      bf16x8 af[4], bfr[4];
#pragma unroll
      for (int i = 0; i < 4; ++i) {
        int row = wm + i * 16 + l15;
        int cc = kk * 4 + quad;
        af[i] = *(const bf16x8*)(As + (row * 8 + (cc ^ (row & 7))) * 8);
      }
#pragma unroll
      for (int j = 0; j < 4; ++j) {
        int row = wn + j * 16 + l15;
        int cc = kk * 4 + quad;
        bfr[j] = *(const bf16x8*)(Bs + (row * 8 + (cc ^ (row & 7))) * 8);
      }
#pragma unroll
      for (int i = 0; i < 4; ++i)
#pragma unroll
        for (int j = 0; j < 4; ++j)
          acc[i][j] = __builtin_amdgcn_mfma_f32_16x16x32_bf16(af[i], bfr[j], acc[i][j], 0, 0, 0);
    }
    __syncthreads();
  }
#pragma unroll
  for (int i = 0; i < 4; ++i)
#pragma unroll
    for (int j = 0; j < 4; ++j) {
      int gm = bm + wm + i * 16 + quad * 4;
      int gn = bn + wn + j * 16 + l15;
      float bv = bias[gn];
#pragma unroll
      for (int r = 0; r < 4; ++r)
        C[(long)(gm + r) * N + gn] = acc[i][j][r] + bv;
    }
}

// fused Q,K,V projection: one launch, N-band selects weight/bias/output
__global__ __launch_bounds__(256, 2) void gemm_qkv(const u16* __restrict__ A,
                                                   const u16* __restrict__ wq,
                                                   const u16* __restrict__ wk,
                                                   const u16* __restrict__ wv,
                                                   const float* __restrict__ bq,
                                                   const float* __restrict__ bk,
                                                   const float* __restrict__ bv,
                                                   float* __restrict__ qf,
                                                   float* __restrict__ kf,
                                                   float* __restrict__ vf) {
  __shared__ u16 As[128 * 64];
  __shared__ u16 Bs[128 * 64];
  const int sel = blockIdx.x / 24;            // 0:q 1:k 2:v
  const int bn = (blockIdx.x % 24) * 128;
  const int bm = blockIdx.y * 128;
  const u16*   B    = (sel == 0) ? wq : (sel == 1) ? wk : wv;
  const float* bias = (sel == 0) ? bq : (sel == 1) ? bk : bv;
  float*       C    = (sel == 0) ? qf : (sel == 1) ? kf : vf;
  gemm_tile(A, B, bias, C, bm, bn, As, Bs);
}

__global__ __launch_bounds__(256, 2) void gemm_bt(const u16* __restrict__ A,
                                                  const u16* __restrict__ B,
                                                  const float* __restrict__ bias,
                                                  float* __restrict__ C) {
  __shared__ u16 As[128 * 64];
  __shared__ u16 Bs[128 * 64];
  gemm_tile(A, B, bias, C, blockIdx.y * 128, blockIdx.x * 128, As, Bs);
}

// --------------------------------------------------- fused RMSNorm + 3D RoPE
// blockIdx.y: 0 -> q, 1 -> k
__global__ __launch_bounds__(256) void rmsnorm_rope(const float* __restrict__ qxf,
                                                    const float* __restrict__ kxf,
                                                    const float* __restrict__ gqp,
                                                    const float* __restrict__ gkp,
                                                    const float* __restrict__ freqs,
                                                    const int* __restrict__ gsz,
                                                    u16* __restrict__ qop,
                                                    u16* __restrict__ kop) {
  const int tok = blockIdx.x;
  const int tid = threadIdx.x;
  const float* xf = blockIdx.y ? kxf : qxf;
  const float* g  = blockIdx.y ? gkp : gqp;
  u16* outp       = blockIdx.y ? kop : qop;
  const float* row = xf + (long)tok * NDIM;
  float4 v[3];
  float ss = 0.f;
#pragma unroll
  for (int p = 0; p < 3; ++p) {
    v[p] = ((const float4*)row)[p * 256 + tid];
    ss += v[p].x * v[p].x + v[p].y * v[p].y + v[p].z * v[p].z + v[p].w * v[p].w;
  }
#pragma unroll
  for (int m = 1; m < 64; m <<= 1) ss += __shfl_xor(ss, m);
  __shared__ float red[4];
  if ((tid & 63) == 0) red[tid >> 6] = ss;
  __syncthreads();
  ss = red[0] + red[1] + red[2] + red[3];
  const float scale = rsqrtf(ss * (1.0f / NDIM) + 1e-6f);

  const int gh = gsz[1], gw = gsz[2];
  const int hw = gh * gw;
  const int fi = tok / hw;
  const int hi = (tok % hw) / gw;
  const int wi = tok % gw;
#pragma unroll
  for (int p = 0; p < 3; ++p) {
    const int e0 = (p * 256 + tid) * 4;
    const float4 gg = ((const float4*)g)[p * 256 + tid];
    const int hh = e0 >> 7;
    const int d = e0 & 127;
    const int c0 = d >> 1;
    int pos0 = (c0 < 22) ? fi : ((c0 < 43) ? hi : wi);
    int pos1 = (c0 + 1 < 22) ? fi : ((c0 + 1 < 43) ? hi : wi);
    float th0 = freqs[pos0 * 64 + c0];
    float th1 = freqs[pos1 * 64 + c0 + 1];
    float s0, cc0, s1, cc1;
    __sincosf(th0, &s0, &cc0);
    __sincosf(th1, &s1, &cc1);
    float x0 = v[p].x * scale * gg.x;
    float x1 = v[p].y * scale * gg.y;
    float x2 = v[p].z * scale * gg.z;
    float x3 = v[p].w * scale * gg.w;
    union { u16 h[4]; uint2 u; } o;
    o.h[0] = f2bf(x0 * cc0 - x1 * s0);
    o.h[1] = f2bf(x0 * s0 + x1 * cc0);
    o.h[2] = f2bf(x2 * cc1 - x3 * s1);
    o.h[3] = f2bf(x2 * s1 + x3 * cc1);
    *(uint2*)(outp + ((long)hh * S_LEN + tok) * HD + d) = o.u;
  }
}

// ----------------------------------------------- V: [S,3072] fp32 -> [3072,S] bf16
__global__ __launch_bounds__(256) void vtrans(const float* __restrict__ vf,
                                              u16* __restrict__ vt) {
  __shared__ float tile[64][65];
  const int c0 = blockIdx.x * 64;
  const int t0 = blockIdx.y * 64;
  const int tid = threadIdx.x;
#pragma unroll
  for (int it = 0; it < 16; ++it) {
    int idx = it * 256 + tid;
    int r = idx >> 6, c = idx & 63;
    tile[r][c] = vf[(long)(t0 + r) * NDIM + c0 + c];
  }
  __syncthreads();
#pragma unroll
  for (int it = 0; it < 16; ++it) {
    int idx = it * 256 + tid;
    int r = idx >> 6, c = idx & 63;
    vt[(long)(c0 + r) * S_LEN + t0 + c] = f2bf(tile[c][r]);
  }
}

// ------------------------------------------------------------ flash attention
// qb,kb: bf16 [NH][S][HD]; vt: bf16 [NH*HD][S]; out: bf16 [S][3072].
// 432 blocks x 256 threads (4 waves x 32 q-rows, Q-tile 128). K-tile = 64,
// double-buffered (prefetch issued right after the single per-iter barrier).
// NO online max: post-RMSNorm |s*SC| <= ~11 so exp is fp32-safe un-shifted;
// row-sum l comes from an MFMA with an all-ones B operand (every column of
// P @ ones holds the row sum, already in per-lane C-layout -> no shuffles,
// no rescale of O). LDS = 2*16(K)+2*16(V)+16(P) = 80 KB -> 2 blocks/CU.
// XCD swizzle: b&7 -> xcd, 3 heads x 18 qtiles per XCD (K+V fits 4MB L2).
__global__ __launch_bounds__(256, 2) void attn_kern(const u16* __restrict__ qb,
                                                    const u16* __restrict__ kb,
                                                    const u16* __restrict__ vt,
                                                    const int* __restrict__ seq_lens,
                                                    u16* __restrict__ ob) {
  __shared__ u16 Kb[2][64 * 128];   // K tile: 64 tok rows x 16 chunks, swz 15
  __shared__ u16 Vb[2][128 * 64];   // V^T tile: 128 d rows x 8 chunks, swz 7
  __shared__ u16 Ps[128 * 64];      // P tile: 128 q rows x 8 chunks, swz 7
  const int b = blockIdx.x;           // 0..431
  const int xcd = b & 7;
  const int slot = b >> 3;            // 0..53
  const int h = xcd * 3 + slot / 18;  // 3 heads per XCD
  const int qt = slot % 18;
  const int t = threadIdx.x;
  const int l = t & 63, w = t >> 6;
  const int l15 = l & 15, quad = l >> 4;
  const int seqlen = seq_lens[0];
  const float SC2 = 0.12753102543f;   // (1/sqrt(128)) * log2(e), for exp2f

  const u16* kbase = kb + (long)h * S_LEN * HD;
  const u16* vbase = vt + (long)h * HD * S_LEN;

  // Q fragments: A-layout m = lane&15, k = quad*8 + j
  bf16x8 qfrag[2][4];
#pragma unroll
  for (int i = 0; i < 2; ++i) {
    const u16* qrow = qb + ((long)h * S_LEN + qt * 128 + w * 32 + i * 16 + l15) * HD + quad * 8;
#pragma unroll
    for (int kk = 0; kk < 4; ++kk) qfrag[i][kk] = *(const bf16x8*)(qrow + kk * 32);
  }

  bf16x8 ones;
#pragma unroll
  for (int i = 0; i < 8; ++i) ones[i] = (__bf16)1.0f;

  floatx4 oacc[2][8];
  floatx4 lacc[2];
#pragma unroll
  for (int i = 0; i < 2; ++i) {
#pragma unroll
    for (int j = 0; j < 8; ++j) oacc[i][j] = {0.f, 0.f, 0.f, 0.f};
    lacc[i] = {0.f, 0.f, 0.f, 0.f};
  }

  // stage K-tile (64x128) + V-tile (128x64) for tile `kt` into buffer `buf`
  auto stage = [&](int kt, int buf) {
#pragma unroll
    for (int i = 0; i < 4; ++i) {
      int p = i * 256 + t;              // 0..1023
      int rk = p >> 4;                  // K: token row 0..63
      int ck = (p & 15) ^ (rk & 15);
      async_load16(kbase + ((long)(kt * 64 + rk)) * HD + ck * 8, &Kb[buf][p * 8]);
      int dv = p >> 3;                  // V: hd row 0..127
      int cv = (p & 7) ^ (dv & 7);
      async_load16(vbase + (long)dv * S_LEN + kt * 64 + cv * 8, &Vb[buf][p * 8]);
    }
  };

  stage(0, 0);

  for (int kt = 0; kt < S_LEN / 64; ++kt) {
    const int cur = kt & 1;
    __syncthreads();                   // tile kt loads done; prev compute done
    if (kt + 1 < S_LEN / 64) stage(kt + 1, cur ^ 1);

    // S = Q K^T  (128q x 64k)
    floatx4 sacc[2][4];
#pragma unroll
    for (int i = 0; i < 2; ++i)
#pragma unroll
      for (int j = 0; j < 4; ++j) sacc[i][j] = {0.f, 0.f, 0.f, 0.f};
#pragma unroll
    for (int kk = 0; kk < 4; ++kk) {
#pragma unroll
      for (int j = 0; j < 4; ++j) {
        int row = j * 16 + l15;
        int cc = kk * 4 + quad;
        bf16x8 bk = *(const bf16x8*)(&Kb[cur][(row * 16 + (cc ^ (row & 15))) * 8]);
        sacc[0][j] = __builtin_amdgcn_mfma_f32_16x16x32_bf16(qfrag[0][kk], bk, sacc[0][j], 0, 0, 0);
        sacc[1][j] = __builtin_amdgcn_mfma_f32_16x16x32_bf16(qfrag[1][kk], bk, sacc[1][j], 0, 0, 0);
      }
    }

    // unshifted softmax numerator: p = 2^(s*SC2)  (masked cols -> 0)
    const bool tail = (kt * 64 + 64 > seqlen);
#pragma unroll
    for (int i = 0; i < 2; ++i)
#pragma unroll
      for (int j = 0; j < 4; ++j)
#pragma unroll
        for (int r = 0; r < 4; ++r) {
          float sv = sacc[i][j][r] * SC2;
          if (tail) {
            int col = kt * 64 + j * 16 + l15;
            if (col >= seqlen) sv = -1e30f;
          }
          sacc[i][j][r] = exp2f(sv);
        }

    // write P into its own buffer (wave-private rows -> no barrier)
#pragma unroll
    for (int i = 0; i < 2; ++i)
#pragma unroll
      for (int j = 0; j < 4; ++j)
#pragma unroll
        for (int r = 0; r < 4; ++r) {
          int rq = w * 32 + i * 16 + quad * 4 + r;   // 0..127
          int ct = j * 16 + l15;                     // 0..63
          int cc = ct >> 3;
          Ps[(rq * 8 + (cc ^ (rq & 7))) * 8 + (ct & 7)] = f2bf(sacc[i][j][r]);
        }

    // O += P V ; l += P @ ones  (A-frags: own rows of Ps)
#pragma unroll
    for (int kl = 0; kl < 2; ++kl) {
      bf16x8 ap[2];
#pragma unroll
      for (int i = 0; i < 2; ++i) {
        int row = w * 32 + i * 16 + l15;
        int cc = kl * 4 + quad;
        ap[i] = *(const bf16x8*)(&Ps[(row * 8 + (cc ^ (row & 7))) * 8]);
      }
      lacc[0] = __builtin_amdgcn_mfma_f32_16x16x32_bf16(ap[0], ones, lacc[0], 0, 0, 0);
      lacc[1] = __builtin_amdgcn_mfma_f32_16x16x32_bf16(ap[1], ones, lacc[1], 0, 0, 0);
#pragma unroll
      for (int j = 0; j < 8; ++j) {
        int d = j * 16 + l15;
        int ccv = kl * 4 + quad;
        bf16x8 bv = *(const bf16x8*)(&Vb[cur][(d * 8 + (ccv ^ (d & 7))) * 8]);
        oacc[0][j] = __builtin_amdgcn_mfma_f32_16x16x32_bf16(ap[0], bv, oacc[0][j], 0, 0, 0);
        oacc[1][j] = __builtin_amdgcn_mfma_f32_16x16x32_bf16(ap[1], bv, oacc[1][j], 0, 0, 0);
      }
    }
  }

  // epilogue: out[t][h*128+d] = O / l
#pragma unroll
  for (int i = 0; i < 2; ++i) {
    float inv[4];
#pragma unroll
    for (int r = 0; r < 4; ++r) inv[r] = 1.0f / lacc[i][r];
#pragma unroll
    for (int j = 0; j < 8; ++j) {
      int gt = qt * 128 + w * 32 + i * 16 + quad * 4;
      int gc = h * HD + j * 16 + l15;
#pragma unroll
      for (int r = 0; r < 4; ++r)
        ob[(long)(gt + r) * NDIM + gc] = f2bf(oacc[i][j][r] * inv[r]);
    }
  }
}

// ----------------------------------------------------------------------------
extern "C" void kernel_launch(void* const* d_in, const int* in_sizes, int n_in,
                              void* d_out, int out_size, void* d_ws, size_t ws_size,
                              hipStream_t stream) {
  const float* x        = (const float*)d_in[0];
  const int*   seq_lens = (const int*)  d_in[1];
  const int*   gsz      = (const int*)  d_in[2];
  const float* freqs    = (const float*)d_in[3];
  const float* wq       = (const float*)d_in[4];
  const float* bq       = (const float*)d_in[5];
  const float* wk       = (const float*)d_in[6];
  const float* bk       = (const float*)d_in[7];
  const float* wv       = (const float*)d_in[8];
  const float* bv       = (const float*)d_in[9];
  const float* wo       = (const float*)d_in[10];
  const float* bo       = (const float*)d_in[11];
  const float* gq       = (const float*)d_in[12];
  const float* gk       = (const float*)d_in[13];
  float* out = (float*)d_out;

  char* ws = (char*)d_ws;
  const size_t SD2 = (size_t)S_LEN * NDIM * 2;   // bf16 [S,3072]
  const size_t W2  = (size_t)NDIM * NDIM * 2;    // bf16 [3072,3072]
  const size_t SD4 = (size_t)S_LEN * NDIM * 4;   // fp32 [S,3072]
  size_t off = 0;
  u16* xb    = (u16*)(ws + off); off += SD2;
  u16* wqb   = (u16*)(ws + off); off += W2;
  u16* wkb   = (u16*)(ws + off); off += W2;
  u16* wvb   = (u16*)(ws + off); off += W2;
  u16* wob   = (u16*)(ws + off); off += W2;
  float* qf  = (float*)(ws + off); off += SD4;
  float* kf  = (float*)(ws + off); off += SD4;
  float* vf  = (float*)(ws + off); off += SD4;
  u16* qbuf  = (u16*)(ws + off); off += SD2;
  u16* kbuf  = (u16*)(ws + off); off += SD2;
  u16* vtb   = (u16*)(ws + off); off += SD2;
  u16* attnb = (u16*)(ws + off); off += SD2;

  cvt_all<<<3456 + 4 * 4608, 256, 0, stream>>>(x, wq, wk, wv, wo,
                                               xb, wqb, wkb, wvb, wob);

  gemm_qkv<<<dim3(72, 18), 256, 0, stream>>>(xb, wqb, wkb, wvb,
                                             bq, bk, bv, qf, kf, vf);

  rmsnorm_rope<<<dim3(S_LEN, 2), 256, 0, stream>>>(qf, kf, gq, gk, freqs, gsz,
                                                   qbuf, kbuf);
  vtrans<<<dim3(NDIM / 64, S_LEN / 64), 256, 0, stream>>>(vf, vtb);

  attn_kern<<<432, 256, 0, stream>>>(qbuf, kbuf, vtb, seq_lens, attnb);

  gemm_bt<<<dim3(NDIM / 128, S_LEN / 128), 256, 0, stream>>>(attnb, wob, bo, out);
}